// Round 1
// baseline (389.355 us; speedup 1.0000x reference)
//
#include <hip/hip_runtime.h>
#include <hip/hip_bf16.h>
#include <math.h>

// Problem constants (from reference): B=8, S=4096, D=2048, E=64, TOP_K=2
#define BB 8
#define SS 4096
#define DD 2048
#define EE 64
#define NCHUNK 32           // S split into 32 chunks of 128 rows
#define ROWS_PER_CHUNK (SS / NCHUNK)   // 128

// Kernel 1: partial column sums of x over S-chunks.
// grid = BB * NCHUNK * 2 = 512 blocks, 256 threads.
// Each block: batch b, S-chunk c, half-of-D h. Thread t handles 4 consecutive
// d's via float4 (coalesced 16B/lane). Writes partial[c][b][d].
__global__ void mean_partial_kernel(const float* __restrict__ x,
                                    float* __restrict__ partial) {
    int blk   = blockIdx.x;
    int h     = blk & 1;          // which half of D
    int c     = (blk >> 1) & (NCHUNK - 1);
    int b     = blk >> 6;         // 512/64 = 8 batches
    int d     = h * (DD / 2) + threadIdx.x * 4;

    const float4* xp = (const float4*)(x + (size_t)b * SS * DD
                                         + (size_t)c * ROWS_PER_CHUNK * DD
                                         + d);
    float4 acc = make_float4(0.f, 0.f, 0.f, 0.f);
    #pragma unroll 4
    for (int r = 0; r < ROWS_PER_CHUNK; ++r) {
        float4 v = xp[(size_t)r * (DD / 4)];
        acc.x += v.x; acc.y += v.y; acc.z += v.z; acc.w += v.w;
    }
    float4* pp = (float4*)(partial + ((size_t)c * BB + b) * DD + d);
    *pp = acc;
}

// Kernel 2: per-batch: reduce chunk partials -> x_flat (mean), GEMV vs W,
// add bias, top-2 + softmax. grid = 8 blocks, 256 threads.
__global__ void gate_kernel(const float* __restrict__ partial,
                            const float* __restrict__ W,
                            const float* __restrict__ bias,
                            float* __restrict__ out) {
    __shared__ float xs[DD];        // 8 KB mean-pooled features
    __shared__ float lred[4][EE];   // quarter-D partial dots
    __shared__ float logits[EE];

    int b   = blockIdx.x;
    int tid = threadIdx.x;

    // Phase A: reduce 32 chunk partials, divide by S
    for (int d = tid; d < DD; d += 256) {
        float s = 0.f;
        #pragma unroll
        for (int c = 0; c < NCHUNK; ++c)
            s += partial[((size_t)c * BB + b) * DD + d];
        xs[d] = s * (1.0f / SS);
    }
    __syncthreads();

    // Phase B: logits. thread -> (expert e = tid&63, quarter q = tid>>6)
    int e = tid & 63;
    int q = tid >> 6;
    const int QD = DD / 4;          // 512
    const float* wp = W + (size_t)e * DD + q * QD;
    const float* xq = xs + q * QD;
    float acc = 0.f;
    #pragma unroll 4
    for (int d = 0; d < QD; ++d) acc += xq[d] * wp[d];
    lred[q][e] = acc;
    __syncthreads();

    if (tid < EE) {
        logits[tid] = lred[0][tid] + lred[1][tid] + lred[2][tid] + lred[3][tid]
                      + bias[tid];
    }
    __syncthreads();

    // Phase D: top-2 (stable: lowest index wins ties, matching lax.top_k),
    // then softmax over the two kept logits.
    if (tid == 0) {
        float m1 = -INFINITY, m2 = -INFINITY;
        int i1 = 0, i2 = 0;
        for (int i = 0; i < EE; ++i) {
            float v = logits[i];
            if (v > m1) { m2 = m1; i2 = i1; m1 = v; i1 = i; }
            else if (v > m2) { m2 = v; i2 = i; }
        }
        float e2 = expf(m2 - m1);
        float inv = 1.0f / (1.0f + e2);
        // outputs concatenated flat: weights [8,2] then indices [8,2]
        out[b * 2 + 0] = inv;
        out[b * 2 + 1] = e2 * inv;
        out[2 * BB + b * 2 + 0] = (float)i1;
        out[2 * BB + b * 2 + 1] = (float)i2;
    }
}

extern "C" void kernel_launch(void* const* d_in, const int* in_sizes, int n_in,
                              void* d_out, int out_size, void* d_ws, size_t ws_size,
                              hipStream_t stream) {
    const float* x  = (const float*)d_in[0];   // [8, 4096, 2048]
    const float* W  = (const float*)d_in[1];   // [64, 2048]
    const float* bb = (const float*)d_in[2];   // [64]
    float* out      = (float*)d_out;           // 32 floats: weights(16) + indices(16)
    float* partial  = (float*)d_ws;            // NCHUNK*B*D floats = 2 MB

    mean_partial_kernel<<<BB * NCHUNK * 2, 256, 0, stream>>>(x, partial);
    gate_kernel<<<BB, 256, 0, stream>>>(partial, W, bb, out);
}